// Round 6
// baseline (228.169 us; speedup 1.0000x reference)
//
#include <hip/hip_runtime.h>
#include <hip/hip_bf16.h>

typedef __attribute__((ext_vector_type(8)))  short bf16x8;
typedef __attribute__((ext_vector_type(16))) float f32x16;

constexpr int SQ = 2048;
constexpr int NB = 2;
constexpr int NH = 16;
constexpr int D  = 64;
constexpr int SROW = NB * NH * D;        // 2048 floats per s step (layout s,b,h,d)
constexpr int BH   = NB * NH;            // 32 (b,h) planes
constexpr int LDP = 72;                  // cvt LDS leading dim (shorts, 144B = b128-aligned)
constexpr int TCH = 4096;                // shorts per 64x64 bf16 tile
constexpr size_t PLANE = (size_t)SQ * D; // 131072 shorts per (b,h) plane

// scale folded into Q: 1/sqrt(64) (coeff cancels) * log2(e) so exp2() is direct
constexpr float QSCALE = 0.125f * 1.44269504088896f;

// one-instruction pack: two fp32 -> bf16x2 dword (RNE)
__device__ __forceinline__ int cvtpk(float lo, float hi) {
    int d;
    asm("v_cvt_pk_bf16_f32 %0, %1, %2" : "=v"(d) : "v"(lo), "v"(hi));
    return d;
}

__device__ __forceinline__ f32x16 z16() {
    f32x16 z;
    #pragma unroll
    for (int i = 0; i < 16; ++i) z[i] = 0.f;
    return z;
}

// ---------------------------------------------------------------------------
// Pre-kernel: K, V fp32 -> bf16 in 32x32x16-MFMA fragment order (layout
// unchanged & verified since R4); this round: float4 global loads +
// v_cvt_pk_bf16_f32 packing (1 VALU vs 3).
//   Per 64x64 tile, 8 fragments (f) of 64 lanes x 16 B:
//   K frag f=(nt*4+ks), lane l: K[nt*32+(l&31)][ks*16+(l>>5)*8 ..+7]
//   V frag f=(dt*4+ts), lane l: V^T[dt*32+(l&31)][ts*16+(l>>5)*8 ..+7]
// ---------------------------------------------------------------------------
__global__ __launch_bounds__(256)
void cvt(const float* __restrict__ K, const float* __restrict__ V,
         short* __restrict__ Kf, short* __restrict__ Vf) {
    __shared__ short Kl[64][LDP];
    __shared__ short Vl[64][LDP];
    const int tid  = threadIdx.x;
    const int tile = blockIdx.x;
    const int bh   = blockIdx.y;
    const int t0   = tile * 64;

    {   // stage K and V tiles into LDS bf16, float4 global reads
        const int r = tid >> 2, c = (tid & 3) * 16;
        const float4* kp4 = (const float4*)(K + (size_t)(t0 + r) * SROW + bh * D + c);
        const float4* vp4 = (const float4*)(V + (size_t)(t0 + r) * SROW + bh * D + c);
        int ok[8], ov[8];
        #pragma unroll
        for (int i = 0; i < 4; ++i) {
            float4 kx = kp4[i], vx = vp4[i];
            ok[2 * i]     = cvtpk(kx.x, kx.y);
            ok[2 * i + 1] = cvtpk(kx.z, kx.w);
            ov[2 * i]     = cvtpk(vx.x, vx.y);
            ov[2 * i + 1] = cvtpk(vx.z, vx.w);
        }
        *(int4*)&Kl[r][c]     = *(int4*)&ok[0];
        *(int4*)&Kl[r][c + 8] = *(int4*)&ok[4];
        *(int4*)&Vl[r][c]     = *(int4*)&ov[0];
        *(int4*)&Vl[r][c + 8] = *(int4*)&ov[4];
    }
    __syncthreads();

    short* kout = Kf + (size_t)bh * PLANE + (size_t)tile * TCH;
    short* vout = Vf + (size_t)bh * PLANE + (size_t)tile * TCH;
    #pragma unroll
    for (int cc = tid; cc < 512; cc += 256) {
        const int f  = cc >> 6, ln = cc & 63, hi = ln >> 5;
        {   // K fragment: aligned b128 LDS read (row stride 144 B)
            const int nt = f >> 2, ks = f & 3;
            const int row = nt * 32 + (ln & 31);
            const int col = ks * 16 + hi * 8;
            *(int4*)&kout[cc * 8] = *(const int4*)&Kl[row][col];
        }
        {   // V^T fragment via LDS transpose gather
            const int dt = f >> 2, ts = f & 3;
            const int d  = dt * 32 + (ln & 31);
            short t8[8];
            #pragma unroll
            for (int j = 0; j < 8; ++j) t8[j] = Vl[ts * 16 + hi * 8 + j][d];
            *(int4*)&vout[cc * 8] = *(int4*)t8;
        }
    }
}

// ---------------------------------------------------------------------------
// Hot kernel v7: makespan-balanced split-K causal flash attention.
//  R5 post-mortem: per-iter cost changes (LDS removal, 32x32, occupancy,
//  staging pipe) all moved <10%; the invariant was the STATIC WORK
//  IMBALANCE: wave tile counts ranged 1..32, so kernel time = the 32-iter
//  wave running a latency-serial tail at 1-2 waves/SIMD.
//  Fix (enabled by our max-free streaming softmax: O and l are ADDITIVE
//  over disjoint t-ranges -> split-K needs no rescaling):
//   - Block = strip-pair {63-p, p} (32-q-row strips; combined tile count
//     == 33 for EVERY p). Wave w takes tiles t = w, w+4, ... of each strip
//     sequentially -> every wave in every block ~8.25 iters. Grid 1024
//     (32 pairs x 32 bh) = 4 IDENTICAL blocks/CU -> balanced under any
//     block->CU assignment; bh = blockIdx&31 keeps bh's K/V on one XCD L2.
//   - Per-wave partial (o0,o1,l) in registers (R5-verified 32x32 pipeline:
//     fragment loads, S-MFMA, exp2 -> cvt_pk -> permlane32_swap -> PV);
//     combined via LDS float atomicAdd; 2 barriers total (init, pre-store).
//   - launch_bounds(256,4): 4 waves/SIMD cover load-at-use latency with
//     TLP (register prefetch was repeatedly defeated by regalloc anyway).
// ---------------------------------------------------------------------------
__global__ __launch_bounds__(256, 4)
void attn_fwd(const float* __restrict__ Q, const short* __restrict__ Kf,
              const short* __restrict__ Vf, float* __restrict__ Out) {
    __shared__ float AccO[2][32][64];   // [strip][q][d] fp32 partials, 16 KB
    __shared__ float AccL[2][32];       // [strip][q] softmax denominators

    const int tid  = threadIdx.x;
    const int wave = tid >> 6;
    const int lane = tid & 63;
    const int q32  = lane & 31;
    const int hi   = lane >> 5;

    const int pair = blockIdx.x >> 5;   // 0..31
    const int bh   = blockIdx.x & 31;   // bh%8 == XCD id

    // ---- zero the accumulators ----
    {
        float* az = &AccO[0][0][0];
        #pragma unroll
        for (int i = tid; i < 4096; i += 256) az[i] = 0.f;
        if (tid < 64) (&AccL[0][0])[tid] = 0.f;
    }
    __syncthreads();

    const short* kb = Kf + (size_t)bh * PLANE;
    const short* vb = Vf + (size_t)bh * PLANE;

    bf16x8 ones;
    #pragma unroll
    for (int i = 0; i < 8; ++i) ones[i] = (short)0x3F80;  // bf16 1.0

    // ---- two strips per block: ph=0 long (63-pair), ph=1 short (pair) ----
    #pragma unroll
    for (int ph = 0; ph < 2; ++ph) {
        const int j = ph ? pair : (63 - pair);   // 32-row strip index
        const int n = (j >> 1) + 1;              // tiles 0..n-1
        if (wave < n) {
            // Q B-fragments for this strip (rows 32j..32j+31)
            bf16x8 qf[4];
            {
                const float* qp = Q + (size_t)(32 * j + q32) * SROW + bh * D + hi * 8;
                #pragma unroll
                for (int ks = 0; ks < 4; ++ks) {
                    float4 x0 = *(const float4*)(qp + ks * 16);
                    float4 x1 = *(const float4*)(qp + ks * 16 + 4);
                    int o4[4];
                    o4[0] = cvtpk(x0.x * QSCALE, x0.y * QSCALE);
                    o4[1] = cvtpk(x0.z * QSCALE, x0.w * QSCALE);
                    o4[2] = cvtpk(x1.x * QSCALE, x1.y * QSCALE);
                    o4[3] = cvtpk(x1.z * QSCALE, x1.w * QSCALE);
                    qf[ks] = *(bf16x8*)o4;
                }
            }

            f32x16 o0 = z16(), o1 = z16(), l = z16();
            const int limit = 32 * (j & 1) + q32;   // causal t-limit in diag tile

            for (int t = wave; t < n; t += 4) {     // 4-way split-K slice
                // ---- K fragments + S^T = K Q^T ----
                const short* kp = kb + (size_t)t * TCH + lane * 8;
                bf16x8 kf[8];
                #pragma unroll
                for (int f = 0; f < 8; ++f) kf[f] = *(const bf16x8*)(kp + f * 512);

                f32x16 sA = z16(), sB = z16();
                __builtin_amdgcn_s_setprio(1);
                #pragma unroll
                for (int ks = 0; ks < 4; ++ks)
                    sA = __builtin_amdgcn_mfma_f32_32x32x16_bf16(kf[ks],     qf[ks], sA, 0, 0, 0);
                #pragma unroll
                for (int ks = 0; ks < 4; ++ks)
                    sB = __builtin_amdgcn_mfma_f32_32x32x16_bf16(kf[4 + ks], qf[ks], sB, 0, 0, 0);
                __builtin_amdgcn_s_setprio(0);

                // ---- exp2 + cvt_pk + permlane32_swap -> PA frags (R5-verified) ----
                const bool diag = (t == n - 1);
                bf16x8 pa[4];
                #pragma unroll
                for (int nt = 0; nt < 2; ++nt) {
                    const f32x16& sN = nt ? sB : sA;
                    float e[16];
                    #pragma unroll
                    for (int r = 0; r < 16; ++r) {
                        const int tl = nt * 32 + (r & 3) + 8 * (r >> 2) + 4 * hi;
                        float xv = sN[r];
                        if (diag && tl > limit) xv = -1e30f;
                        e[r] = __builtin_exp2f(xv);
                    }
                    int dw[8];
                    #pragma unroll
                    for (int i = 0; i < 8; ++i) dw[i] = cvtpk(e[2 * i], e[2 * i + 1]);
                    #pragma unroll
                    for (int half = 0; half < 2; ++half) {
                        int a0 = dw[4 * half + 0], b0 = dw[4 * half + 2];
                        int a1 = dw[4 * half + 1], b1 = dw[4 * half + 3];
                        asm("v_permlane32_swap_b32 %0, %1" : "+v"(a0), "+v"(b0));
                        asm("v_permlane32_swap_b32 %0, %1" : "+v"(a1), "+v"(b1));
                        int4 w = make_int4(a0, a1, b0, b1);
                        pa[nt * 2 + half] = *(bf16x8*)&w;
                    }
                }

                // ---- O += P V ; l += P*1 (V fragments at use, TLP-covered) ----
                const short* vp = vb + (size_t)t * TCH + lane * 8;
                __builtin_amdgcn_s_setprio(1);
                #pragma unroll
                for (int ts = 0; ts < 4; ++ts) {
                    bf16x8 v0 = *(const bf16x8*)(vp + ts * 512);
                    bf16x8 v1 = *(const bf16x8*)(vp + (4 + ts) * 512);
                    l  = __builtin_amdgcn_mfma_f32_32x32x16_bf16(pa[ts], ones, l,  0, 0, 0);
                    o0 = __builtin_amdgcn_mfma_f32_32x32x16_bf16(pa[ts], v0,   o0, 0, 0, 0);
                    o1 = __builtin_amdgcn_mfma_f32_32x32x16_bf16(pa[ts], v1,   o1, 0, 0, 0);
                }
                __builtin_amdgcn_s_setprio(0);
            }

            // ---- combine partials into LDS (additive split-K merge) ----
            #pragma unroll
            for (int r = 0; r < 16; ++r) {
                const int qr = (r & 3) + 8 * (r >> 2) + 4 * hi;
                atomicAdd(&AccO[ph][qr][q32],      o0[r]);
                atomicAdd(&AccO[ph][qr][32 + q32], o1[r]);
                if (q32 == 0) atomicAdd(&AccL[ph][qr], l[r]);
            }
        }
    }
    __syncthreads();

    // ---- epilogue: normalize + coalesced store; wave w -> rows 16w..16w+15 ----
    #pragma unroll
    for (int k = 0; k < 16; ++k) {
        const int rr   = wave * 16 + k;       // 0..63 over the two strips
        const int sidx = rr >> 5;
        const int r32  = rr & 31;
        const int j    = sidx ? pair : (63 - pair);
        const float inv = 1.f / AccL[sidx][r32];
        Out[(size_t)(32 * j + r32) * SROW + bh * D + lane] = AccO[sidx][r32][lane] * inv;
    }
}

extern "C" void kernel_launch(void* const* d_in, const int* in_sizes, int n_in,
                              void* d_out, int out_size, void* d_ws, size_t ws_size,
                              hipStream_t stream) {
    const float* Q = (const float*)d_in[0];
    const float* K = (const float*)d_in[1];
    const float* V = (const float*)d_in[2];
    // d_in[3] (attention_mask) is pure causal — folded into the kernel.
    float* Out = (float*)d_out;

    // d_ws layout: Kf | Vf (bf16, fragment order), 8 MB each
    short* Kf = (short*)d_ws;
    short* Vf = Kf + (size_t)BH * PLANE;

    dim3 gcvt(SQ / 64, BH);
    cvt<<<gcvt, 256, 0, stream>>>(K, V, Kf, Vf);
    attn_fwd<<<dim3(1024), 256, 0, stream>>>(Q, Kf, Vf, Out);
}

// Round 7
// 211.909 us; speedup vs baseline: 1.0767x; 1.0767x over previous
//
#include <hip/hip_runtime.h>
#include <hip/hip_bf16.h>

typedef __attribute__((ext_vector_type(8)))  short bf16x8;
typedef __attribute__((ext_vector_type(16))) float f32x16;

constexpr int SQ = 2048;
constexpr int NB = 2;
constexpr int NH = 16;
constexpr int D  = 64;
constexpr int SROW = NB * NH * D;        // 2048 floats per s step (layout s,b,h,d)
constexpr int BH   = NB * NH;            // 32 (b,h) planes
constexpr int LDP = 72;                  // cvt LDS leading dim (shorts, 144B = b128-aligned)
constexpr int TCH = 4096;                // shorts per 64x64 bf16 tile
constexpr size_t PLANE = (size_t)SQ * D; // 131072 shorts per (b,h) plane

// scale folded into Q: 1/sqrt(64) (coeff cancels) * log2(e) so exp2() is direct
constexpr float QSCALE = 0.125f * 1.44269504088896f;

// one-instruction pack: two fp32 -> bf16x2 dword (RNE)
__device__ __forceinline__ int cvtpk(float lo, float hi) {
    int d;
    asm("v_cvt_pk_bf16_f32 %0, %1, %2" : "=v"(d) : "v"(lo), "v"(hi));
    return d;
}

__device__ __forceinline__ f32x16 z16() {
    f32x16 z;
    #pragma unroll
    for (int i = 0; i < 16; ++i) z[i] = 0.f;
    return z;
}

// ---------------------------------------------------------------------------
// Pre-kernel (unchanged from R6, verified): K, V fp32 -> bf16 in 32x32x16-MFMA
// fragment order; float4 global loads + v_cvt_pk_bf16_f32 packing.
//   Per 64x64 tile, 8 fragments (f) of 64 lanes x 16 B:
//   K frag f=(nt*4+ks), lane l: K[nt*32+(l&31)][ks*16+(l>>5)*8 ..+7]
//   V frag f=(dt*4+ts), lane l: V^T[dt*32+(l&31)][ts*16+(l>>5)*8 ..+7]
// ---------------------------------------------------------------------------
__global__ __launch_bounds__(256)
void cvt(const float* __restrict__ K, const float* __restrict__ V,
         short* __restrict__ Kf, short* __restrict__ Vf) {
    __shared__ short Kl[64][LDP];
    __shared__ short Vl[64][LDP];
    const int tid  = threadIdx.x;
    const int tile = blockIdx.x;
    const int bh   = blockIdx.y;
    const int t0   = tile * 64;

    {   // stage K and V tiles into LDS bf16, float4 global reads
        const int r = tid >> 2, c = (tid & 3) * 16;
        const float4* kp4 = (const float4*)(K + (size_t)(t0 + r) * SROW + bh * D + c);
        const float4* vp4 = (const float4*)(V + (size_t)(t0 + r) * SROW + bh * D + c);
        int ok[8], ov[8];
        #pragma unroll
        for (int i = 0; i < 4; ++i) {
            float4 kx = kp4[i], vx = vp4[i];
            ok[2 * i]     = cvtpk(kx.x, kx.y);
            ok[2 * i + 1] = cvtpk(kx.z, kx.w);
            ov[2 * i]     = cvtpk(vx.x, vx.y);
            ov[2 * i + 1] = cvtpk(vx.z, vx.w);
        }
        *(int4*)&Kl[r][c]     = *(int4*)&ok[0];
        *(int4*)&Kl[r][c + 8] = *(int4*)&ok[4];
        *(int4*)&Vl[r][c]     = *(int4*)&ov[0];
        *(int4*)&Vl[r][c + 8] = *(int4*)&ov[4];
    }
    __syncthreads();

    short* kout = Kf + (size_t)bh * PLANE + (size_t)tile * TCH;
    short* vout = Vf + (size_t)bh * PLANE + (size_t)tile * TCH;
    #pragma unroll
    for (int cc = tid; cc < 512; cc += 256) {
        const int f  = cc >> 6, ln = cc & 63, hi = ln >> 5;
        {   // K fragment: aligned b128 LDS read (row stride 144 B)
            const int nt = f >> 2, ks = f & 3;
            const int row = nt * 32 + (ln & 31);
            const int col = ks * 16 + hi * 8;
            *(int4*)&kout[cc * 8] = *(const int4*)&Kl[row][col];
        }
        {   // V^T fragment via LDS transpose gather
            const int dt = f >> 2, ts = f & 3;
            const int d  = dt * 32 + (ln & 31);
            short t8[8];
            #pragma unroll
            for (int j = 0; j < 8; ++j) t8[j] = Vl[ts * 16 + hi * 8 + j][d];
            *(int4*)&vout[cc * 8] = *(int4*)t8;
        }
    }
}

// ---------------------------------------------------------------------------
// Hot kernel v8: balanced split-K, SPILL-FREE.
//  R6 post-mortem: the balanced structure was correct but launch_bounds(256,4)
//  capped VGPR at 128 < ~150 live state -> scratch spills (WRITE_SIZE
//  16->35 MB, FETCH 16.4->29.5 MB, MfmaUtil 6.5%, 130us). The makespan theory
//  was never actually measured.
//  This round: identical structure with the spill removed and one VALU cut:
//   - __launch_bounds__(256,3): per-wave budget 512/3 ~= 170 VGPR > 150 live.
//     3 identical blocks resident/CU (grid 1024 = 4 blocks/CU total, uniform
//     33-tile blocks -> no long-tail wave; R5's worst wave was 32 iters,
//     here every wave ~8.25).
//   - Causal mask OUT of the hot path: main-loop iters compute exp2 unmasked;
//     only t == n-1 (one iter, one wave per strip) runs a 32-cndmask zeroing
//     pass under a wave-uniform branch (e -> 0 where t > limit; exp2 overflow
//     in the masked region is replaced by select, never multiplied).
//   - Everything else byte-identical to R6 for attribution: strip-pair
//     {63-p, p} blocks (33 tiles each), 4-way split-K per strip, register
//     partials -> LDS atomicAdd combine, 2 barriers, bh = blockIdx&31 ->
//     XCD-local K/V, R5-verified in-register P exchange (cvt_pk +
//     permlane32_swap), s_setprio around MFMA clusters.
// ---------------------------------------------------------------------------
__global__ __launch_bounds__(256, 3)
void attn_fwd(const float* __restrict__ Q, const short* __restrict__ Kf,
              const short* __restrict__ Vf, float* __restrict__ Out) {
    __shared__ float AccO[2][32][64];   // [strip][q][d] fp32 partials, 16 KB
    __shared__ float AccL[2][32];       // [strip][q] softmax denominators

    const int tid  = threadIdx.x;
    const int wave = tid >> 6;
    const int lane = tid & 63;
    const int q32  = lane & 31;
    const int hi   = lane >> 5;

    const int pair = blockIdx.x >> 5;   // 0..31
    const int bh   = blockIdx.x & 31;   // bh%8 == XCD id

    // ---- zero the accumulators ----
    {
        float* az = &AccO[0][0][0];
        #pragma unroll
        for (int i = tid; i < 4096; i += 256) az[i] = 0.f;
        if (tid < 64) (&AccL[0][0])[tid] = 0.f;
    }
    __syncthreads();

    const short* kb = Kf + (size_t)bh * PLANE;
    const short* vb = Vf + (size_t)bh * PLANE;

    bf16x8 ones;
    #pragma unroll
    for (int i = 0; i < 8; ++i) ones[i] = (short)0x3F80;  // bf16 1.0

    // ---- two strips per block: ph=0 long (63-pair), ph=1 short (pair) ----
    #pragma unroll
    for (int ph = 0; ph < 2; ++ph) {
        const int j = ph ? pair : (63 - pair);   // 32-row strip index
        const int n = (j >> 1) + 1;              // tiles 0..n-1
        if (wave < n) {
            // Q B-fragments for this strip (rows 32j..32j+31)
            bf16x8 qf[4];
            {
                const float* qp = Q + (size_t)(32 * j + q32) * SROW + bh * D + hi * 8;
                #pragma unroll
                for (int ks = 0; ks < 4; ++ks) {
                    float4 x0 = *(const float4*)(qp + ks * 16);
                    float4 x1 = *(const float4*)(qp + ks * 16 + 4);
                    int o4[4];
                    o4[0] = cvtpk(x0.x * QSCALE, x0.y * QSCALE);
                    o4[1] = cvtpk(x0.z * QSCALE, x0.w * QSCALE);
                    o4[2] = cvtpk(x1.x * QSCALE, x1.y * QSCALE);
                    o4[3] = cvtpk(x1.z * QSCALE, x1.w * QSCALE);
                    qf[ks] = *(bf16x8*)o4;
                }
            }

            f32x16 o0 = z16(), o1 = z16(), l = z16();
            const int limit = 32 * (j & 1) + q32;   // causal t-limit in diag tile

            for (int t = wave; t < n; t += 4) {     // 4-way split-K slice
                // ---- K fragments + S^T = K Q^T ----
                const short* kp = kb + (size_t)t * TCH + lane * 8;
                bf16x8 kf[8];
                #pragma unroll
                for (int f = 0; f < 8; ++f) kf[f] = *(const bf16x8*)(kp + f * 512);

                f32x16 sA = z16(), sB = z16();
                __builtin_amdgcn_s_setprio(1);
                #pragma unroll
                for (int ks = 0; ks < 4; ++ks)
                    sA = __builtin_amdgcn_mfma_f32_32x32x16_bf16(kf[ks],     qf[ks], sA, 0, 0, 0);
                #pragma unroll
                for (int ks = 0; ks < 4; ++ks)
                    sB = __builtin_amdgcn_mfma_f32_32x32x16_bf16(kf[4 + ks], qf[ks], sB, 0, 0, 0);
                __builtin_amdgcn_s_setprio(0);

                // ---- exp2 (unmasked hot path) ----
                float e[32];
                #pragma unroll
                for (int r = 0; r < 16; ++r) e[r]      = __builtin_exp2f(sA[r]);
                #pragma unroll
                for (int r = 0; r < 16; ++r) e[16 + r] = __builtin_exp2f(sB[r]);

                // ---- diag-only causal zeroing (wave-uniform branch) ----
                if (t == n - 1) {
                    #pragma unroll
                    for (int nt = 0; nt < 2; ++nt)
                        #pragma unroll
                        for (int r = 0; r < 16; ++r) {
                            const int tl = nt * 32 + (r & 3) + 8 * (r >> 2) + 4 * hi;
                            if (tl > limit) e[nt * 16 + r] = 0.f;
                        }
                }

                // ---- cvt_pk + permlane32_swap -> PA frags (R5-verified) ----
                bf16x8 pa[4];
                #pragma unroll
                for (int nt = 0; nt < 2; ++nt) {
                    int dw[8];
                    #pragma unroll
                    for (int i = 0; i < 8; ++i)
                        dw[i] = cvtpk(e[nt * 16 + 2 * i], e[nt * 16 + 2 * i + 1]);
                    #pragma unroll
                    for (int half = 0; half < 2; ++half) {
                        int a0 = dw[4 * half + 0], b0 = dw[4 * half + 2];
                        int a1 = dw[4 * half + 1], b1 = dw[4 * half + 3];
                        asm("v_permlane32_swap_b32 %0, %1" : "+v"(a0), "+v"(b0));
                        asm("v_permlane32_swap_b32 %0, %1" : "+v"(a1), "+v"(b1));
                        int4 w = make_int4(a0, a1, b0, b1);
                        pa[nt * 2 + half] = *(bf16x8*)&w;
                    }
                }

                // ---- O += P V ; l += P*1 (V fragments at use, TLP-covered) ----
                const short* vp = vb + (size_t)t * TCH + lane * 8;
                __builtin_amdgcn_s_setprio(1);
                #pragma unroll
                for (int ts = 0; ts < 4; ++ts) {
                    bf16x8 v0 = *(const bf16x8*)(vp + ts * 512);
                    bf16x8 v1 = *(const bf16x8*)(vp + (4 + ts) * 512);
                    l  = __builtin_amdgcn_mfma_f32_32x32x16_bf16(pa[ts], ones, l,  0, 0, 0);
                    o0 = __builtin_amdgcn_mfma_f32_32x32x16_bf16(pa[ts], v0,   o0, 0, 0, 0);
                    o1 = __builtin_amdgcn_mfma_f32_32x32x16_bf16(pa[ts], v1,   o1, 0, 0, 0);
                }
                __builtin_amdgcn_s_setprio(0);
            }

            // ---- combine partials into LDS (additive split-K merge) ----
            #pragma unroll
            for (int r = 0; r < 16; ++r) {
                const int qr = (r & 3) + 8 * (r >> 2) + 4 * hi;
                atomicAdd(&AccO[ph][qr][q32],      o0[r]);
                atomicAdd(&AccO[ph][qr][32 + q32], o1[r]);
                if (q32 == 0) atomicAdd(&AccL[ph][qr], l[r]);
            }
        }
    }
    __syncthreads();

    // ---- epilogue: normalize + coalesced store; wave w -> rows 16w..16w+15 ----
    #pragma unroll
    for (int k = 0; k < 16; ++k) {
        const int rr   = wave * 16 + k;       // 0..63 over the two strips
        const int sidx = rr >> 5;
        const int r32  = rr & 31;
        const int j    = sidx ? pair : (63 - pair);
        const float inv = 1.f / AccL[sidx][r32];
        Out[(size_t)(32 * j + r32) * SROW + bh * D + lane] = AccO[sidx][r32][lane] * inv;
    }
}

extern "C" void kernel_launch(void* const* d_in, const int* in_sizes, int n_in,
                              void* d_out, int out_size, void* d_ws, size_t ws_size,
                              hipStream_t stream) {
    const float* Q = (const float*)d_in[0];
    const float* K = (const float*)d_in[1];
    const float* V = (const float*)d_in[2];
    // d_in[3] (attention_mask) is pure causal — folded into the kernel.
    float* Out = (float*)d_out;

    // d_ws layout: Kf | Vf (bf16, fragment order), 8 MB each
    short* Kf = (short*)d_ws;
    short* Vf = Kf + (size_t)BH * PLANE;

    dim3 gcvt(SQ / 64, BH);
    cvt<<<gcvt, 256, 0, stream>>>(K, V, Kf, Vf);
    attn_fwd<<<dim3(1024), 256, 0, stream>>>(Q, Kf, Vf, Out);
}

// Round 8
// 150.004 us; speedup vs baseline: 1.5211x; 1.4127x over previous
//
#include <hip/hip_runtime.h>
#include <hip/hip_bf16.h>

typedef __attribute__((ext_vector_type(8)))  short bf16x8;
typedef __attribute__((ext_vector_type(16))) float f32x16;

constexpr int SQ = 2048;
constexpr int NB = 2;
constexpr int NH = 16;
constexpr int D  = 64;
constexpr int SROW = NB * NH * D;        // 2048 floats per s step (layout s,b,h,d)
constexpr int BH   = NB * NH;            // 32 (b,h) planes
constexpr int LDP = 72;                  // cvt LDS leading dim (shorts, 144B = b128-aligned)
constexpr int TCH = 4096;                // shorts per 64x64 bf16 tile
constexpr size_t PLANE = (size_t)SQ * D; // 131072 shorts per (b,h) plane

// scale folded into Q: 1/sqrt(64) (coeff cancels) * log2(e) so exp2() is direct
constexpr float QSCALE = 0.125f * 1.44269504088896f;

// one-instruction pack: two fp32 -> bf16x2 dword (RNE)
__device__ __forceinline__ int cvtpk(float lo, float hi) {
    int d;
    asm("v_cvt_pk_bf16_f32 %0, %1, %2" : "=v"(d) : "v"(lo), "v"(hi));
    return d;
}

__device__ __forceinline__ f32x16 z16() {
    f32x16 z;
    #pragma unroll
    for (int i = 0; i < 16; ++i) z[i] = 0.f;
    return z;
}

// ---------------------------------------------------------------------------
// Pre-kernel (unchanged, verified): K, V fp32 -> bf16 in 32x32x16-MFMA
// fragment order; float4 global loads + v_cvt_pk_bf16_f32 packing.
//   Per 64x64 tile, 8 fragments (f) of 64 lanes x 16 B:
//   K frag f=(nt*4+ks), lane l: K[nt*32+(l&31)][ks*16+(l>>5)*8 ..+7]
//   V frag f=(dt*4+ts), lane l: V^T[dt*32+(l&31)][ts*16+(l>>5)*8 ..+7]
// ---------------------------------------------------------------------------
__global__ __launch_bounds__(256)
void cvt(const float* __restrict__ K, const float* __restrict__ V,
         short* __restrict__ Kf, short* __restrict__ Vf) {
    __shared__ short Kl[64][LDP];
    __shared__ short Vl[64][LDP];
    const int tid  = threadIdx.x;
    const int tile = blockIdx.x;
    const int bh   = blockIdx.y;
    const int t0   = tile * 64;

    {   // stage K and V tiles into LDS bf16, float4 global reads
        const int r = tid >> 2, c = (tid & 3) * 16;
        const float4* kp4 = (const float4*)(K + (size_t)(t0 + r) * SROW + bh * D + c);
        const float4* vp4 = (const float4*)(V + (size_t)(t0 + r) * SROW + bh * D + c);
        int ok[8], ov[8];
        #pragma unroll
        for (int i = 0; i < 4; ++i) {
            float4 kx = kp4[i], vx = vp4[i];
            ok[2 * i]     = cvtpk(kx.x, kx.y);
            ok[2 * i + 1] = cvtpk(kx.z, kx.w);
            ov[2 * i]     = cvtpk(vx.x, vx.y);
            ov[2 * i + 1] = cvtpk(vx.z, vx.w);
        }
        *(int4*)&Kl[r][c]     = *(int4*)&ok[0];
        *(int4*)&Kl[r][c + 8] = *(int4*)&ok[4];
        *(int4*)&Vl[r][c]     = *(int4*)&ov[0];
        *(int4*)&Vl[r][c + 8] = *(int4*)&ov[4];
    }
    __syncthreads();

    short* kout = Kf + (size_t)bh * PLANE + (size_t)tile * TCH;
    short* vout = Vf + (size_t)bh * PLANE + (size_t)tile * TCH;
    #pragma unroll
    for (int cc = tid; cc < 512; cc += 256) {
        const int f  = cc >> 6, ln = cc & 63, hi = ln >> 5;
        {   // K fragment: aligned b128 LDS read (row stride 144 B)
            const int nt = f >> 2, ks = f & 3;
            const int row = nt * 32 + (ln & 31);
            const int col = ks * 16 + hi * 8;
            *(int4*)&kout[cc * 8] = *(const int4*)&Kl[row][col];
        }
        {   // V^T fragment via LDS transpose gather
            const int dt = f >> 2, ts = f & 3;
            const int d  = dt * 32 + (ln & 31);
            short t8[8];
            #pragma unroll
            for (int j = 0; j < 8; ++j) t8[j] = Vl[ts * 16 + hi * 8 + j][d];
            *(int4*)&vout[cc * 8] = *(int4*)t8;
        }
    }
}

// ---------------------------------------------------------------------------
// Hot kernel v9: counted-vmcnt DMA pipeline (T3/T4), R5 decomposition.
//  R5+R7 post-mortem: per-wave-iter cost is ~3.3K cy (R5, L1-shared) to
//  ~8.5K cy (R7, split-K/L2) vs ~500 cy of issue work -> the kernel is
//  ~90% exposed at-use K/V load latency, serialized per iteration.
//  Register prefetch is impossible (live state + 64 fragment VGPRs beats
//  every cap; defeated in R2/R5/R6). The zero-VGPR fix:
//   - global_load_lds DMA staging, 3 buffers, DEPTH-2 pipeline:
//       iter t: s_waitcnt vmcnt(4)   [tile t landed; t+1 stays in flight]
//               s_barrier
//               issue stage(t+2) -> buffer freed at t-1
//               compute tile t from LDS (all 4 waves share it)
//     vmcnt never drains to 0 mid-loop (R3's mistake via __syncthreads).
//     Per wave: 4 DMA loads/tile (2 K + 2 V chunks), steady outstanding 8.
//   - raw s_barrier (no implicit vmcnt(0)); sched_barrier(0) fences the
//     asm waits (guide rule #18). Wave's own prior-iter ds_reads are
//     consumed by MFMAs before the barrier -> buffer reuse is safe.
//   - compute body = R5-verified: 32x32 MFMA, in-register P exchange
//     (cvt_pk + permlane32_swap), diag-only causal zeroing (R7-verified),
//     direct store epilogue (R5-verified).
//  LDS 48 KB, launch_bounds(256,2): 2 blocks/CU, VGPR budget 256 (no spill).
// ---------------------------------------------------------------------------
__global__ __launch_bounds__(256, 2)
void attn_fwd(const float* __restrict__ Q, const short* __restrict__ Kf,
              const short* __restrict__ Vf, float* __restrict__ Out) {
    __shared__ __align__(16) short Kls[3][4096];   // 3 x 8 KB K tile
    __shared__ __align__(16) short Vls[3][4096];   // 3 x 8 KB V tile

    const int tid  = threadIdx.x;
    const int wave = tid >> 6;
    const int lane = tid & 63;
    const int q32  = lane & 31;
    const int hi   = lane >> 5;

    const int c  = blockIdx.x & 255;
    const int g  = blockIdx.x >> 8;
    const int u  = c >> 5;              // 0..7
    const int bh = c & 31;              // bh%8 == XCD id
    const int a  = g ? u : (15 - u);    // strip128 id, long strips first
    const int sw   = 2 * a + (wave >> 1);   // this wave's last tile
    const int smax = 2 * a + 1;             // block's last tile
    const int limit = 32 * (wave & 1) + q32;

    const short* kb = Kf + (size_t)bh * PLANE;
    const short* vb = Vf + (size_t)bh * PLANE;

    // stage tile t into buffer buf: wave w copies K chunks {2w,2w+1} and
    // V chunks {2w,2w+1}; each chunk = 64 lanes x 16 B, LDS dest linear
    // (wave-uniform base; HW adds lane*16).  [R3-verified pattern]
    auto stageT = [&](int t, int buf) {
        const short* gK = kb + (size_t)t * TCH + wave * 1024 + lane * 8;
        const short* gV = vb + (size_t)t * TCH + wave * 1024 + lane * 8;
        short* dK = &Kls[buf][wave * 1024];
        short* dV = &Vls[buf][wave * 1024];
        #pragma unroll
        for (int i = 0; i < 2; ++i) {
            __builtin_amdgcn_global_load_lds(
                (__attribute__((address_space(1))) void*)(gK + i * 512),
                (__attribute__((address_space(3))) void*)(dK + i * 512), 16, 0, 0);
            __builtin_amdgcn_global_load_lds(
                (__attribute__((address_space(1))) void*)(gV + i * 512),
                (__attribute__((address_space(3))) void*)(dV + i * 512), 16, 0, 0);
        }
    };

    // prologue: stage tiles 0 and 1 (depth-2 fill; 8 loads outstanding)
    stageT(0, 0);
    stageT(1, 1);

    // ---- Q B-fragments (overlap with DMA flight): R5-verified ----
    bf16x8 qf[4];
    {
        const int qrow = a * 128 + wave * 32 + q32;
        const float* qp = Q + (size_t)qrow * SROW + bh * D + hi * 8;
        #pragma unroll
        for (int ks = 0; ks < 4; ++ks) {
            float4 x0 = *(const float4*)(qp + ks * 16);
            float4 x1 = *(const float4*)(qp + ks * 16 + 4);
            int o4[4];
            o4[0] = cvtpk(x0.x * QSCALE, x0.y * QSCALE);
            o4[1] = cvtpk(x0.z * QSCALE, x0.w * QSCALE);
            o4[2] = cvtpk(x1.x * QSCALE, x1.y * QSCALE);
            o4[3] = cvtpk(x1.z * QSCALE, x1.w * QSCALE);
            qf[ks] = *(bf16x8*)o4;
        }
    }

    f32x16 o0 = z16(), o1 = z16(), l = z16();
    bf16x8 ones;
    #pragma unroll
    for (int i = 0; i < 8; ++i) ones[i] = (short)0x3F80;  // bf16 1.0

    int bc = 0;   // compute buffer for tile t (rotates 0,1,2)
    for (int t = 0; t <= smax; ++t) {
        // ---- wait for tile t only: 4 loads of t+1 stay in flight ----
        if (t < smax) { asm volatile("s_waitcnt vmcnt(4)" ::: "memory"); }
        else          { asm volatile("s_waitcnt vmcnt(0)" ::: "memory"); }
        __builtin_amdgcn_sched_barrier(0);
        __builtin_amdgcn_s_barrier();
        __builtin_amdgcn_sched_barrier(0);

        // ---- issue stage(t+2) into the buffer freed at iter t-1 ----
        if (t + 2 <= smax) stageT(t + 2, bc == 0 ? 2 : bc - 1);

        if (t <= sw) {   // wave-uniform: waves 0,1 skip the block's last tile
            const short* kc = Kls[bc];
            const short* vc = Vls[bc];

            // ---- K fragments from LDS + S^T = K Q^T ----
            bf16x8 kfr[8];
            #pragma unroll
            for (int f = 0; f < 8; ++f)
                kfr[f] = *(const bf16x8*)(kc + f * 512 + lane * 8);

            f32x16 sA = z16(), sB = z16();
            __builtin_amdgcn_s_setprio(1);
            #pragma unroll
            for (int ks = 0; ks < 4; ++ks)
                sA = __builtin_amdgcn_mfma_f32_32x32x16_bf16(kfr[ks],     qf[ks], sA, 0, 0, 0);
            #pragma unroll
            for (int ks = 0; ks < 4; ++ks)
                sB = __builtin_amdgcn_mfma_f32_32x32x16_bf16(kfr[4 + ks], qf[ks], sB, 0, 0, 0);
            __builtin_amdgcn_s_setprio(0);

            // ---- exp2 (unmasked hot path) ----
            float e[32];
            #pragma unroll
            for (int r = 0; r < 16; ++r) e[r]      = __builtin_exp2f(sA[r]);
            #pragma unroll
            for (int r = 0; r < 16; ++r) e[16 + r] = __builtin_exp2f(sB[r]);

            // ---- diag-only causal zeroing (wave-uniform branch) ----
            if (t == sw) {
                #pragma unroll
                for (int nt = 0; nt < 2; ++nt)
                    #pragma unroll
                    for (int r = 0; r < 16; ++r) {
                        const int tl = nt * 32 + (r & 3) + 8 * (r >> 2) + 4 * hi;
                        if (tl > limit) e[nt * 16 + r] = 0.f;
                    }
            }

            // ---- cvt_pk + permlane32_swap -> PA frags (R5-verified) ----
            bf16x8 pa[4];
            #pragma unroll
            for (int nt = 0; nt < 2; ++nt) {
                int dw[8];
                #pragma unroll
                for (int i = 0; i < 8; ++i)
                    dw[i] = cvtpk(e[nt * 16 + 2 * i], e[nt * 16 + 2 * i + 1]);
                #pragma unroll
                for (int half = 0; half < 2; ++half) {
                    int a0 = dw[4 * half + 0], b0 = dw[4 * half + 2];
                    int a1 = dw[4 * half + 1], b1 = dw[4 * half + 3];
                    asm("v_permlane32_swap_b32 %0, %1" : "+v"(a0), "+v"(b0));
                    asm("v_permlane32_swap_b32 %0, %1" : "+v"(a1), "+v"(b1));
                    int4 w = make_int4(a0, a1, b0, b1);
                    pa[nt * 2 + half] = *(bf16x8*)&w;
                }
            }

            // ---- O += P V ; l += P*1 (V fragments from LDS) ----
            __builtin_amdgcn_s_setprio(1);
            #pragma unroll
            for (int ts = 0; ts < 4; ++ts) {
                bf16x8 v0 = *(const bf16x8*)(vc + ts * 512 + lane * 8);
                bf16x8 v1 = *(const bf16x8*)(vc + (4 + ts) * 512 + lane * 8);
                l  = __builtin_amdgcn_mfma_f32_32x32x16_bf16(pa[ts], ones, l,  0, 0, 0);
                o0 = __builtin_amdgcn_mfma_f32_32x32x16_bf16(pa[ts], v0,   o0, 0, 0, 0);
                o1 = __builtin_amdgcn_mfma_f32_32x32x16_bf16(pa[ts], v1,   o1, 0, 0, 0);
            }
            __builtin_amdgcn_s_setprio(0);
        }

        bc = (bc == 2) ? 0 : bc + 1;
    }

    // ---- epilogue: normalize, store fp32 (R5-verified) ----
    #pragma unroll
    for (int r = 0; r < 16; ++r) {
        const int qr   = (r & 3) + 8 * (r >> 2) + 4 * hi;
        const float inv = 1.f / l[r];
        float* op = Out + (size_t)(a * 128 + wave * 32 + qr) * SROW + bh * D;
        op[q32]      = o0[r] * inv;
        op[32 + q32] = o1[r] * inv;
    }
}

extern "C" void kernel_launch(void* const* d_in, const int* in_sizes, int n_in,
                              void* d_out, int out_size, void* d_ws, size_t ws_size,
                              hipStream_t stream) {
    const float* Q = (const float*)d_in[0];
    const float* K = (const float*)d_in[1];
    const float* V = (const float*)d_in[2];
    // d_in[3] (attention_mask) is pure causal — folded into the kernel.
    float* Out = (float*)d_out;

    // d_ws layout: Kf | Vf (bf16, fragment order), 8 MB each
    short* Kf = (short*)d_ws;
    short* Vf = Kf + (size_t)BH * PLANE;

    dim3 gcvt(SQ / 64, BH);
    cvt<<<gcvt, 256, 0, stream>>>(K, V, Kf, Vf);
    attn_fwd<<<dim3(512), 256, 0, stream>>>(Q, Kf, Vf, Out);
}